// Round 3
// baseline (4644.008 us; speedup 1.0000x reference)
//
#include <hip/hip_runtime.h>
#include <hip/hip_fp16.h>

// CNF: B=262144 samples, D=8, H=64.
// outputs: dz_dt (B*8) | dlogp_z_dt (B) | g (B), all f32, concat flat.

#define BATCH 262144
#define DD 8
#define HH 64

__device__ __forceinline__ float tanh_fast(float x) {
    // tanh(x) = 1 - 2/(exp(2x)+1), exp via exp2. Handles +-inf saturation.
    float e = __builtin_amdgcn_exp2f(x * 2.8853900817779268f); // 2*log2(e)
    return 1.0f - 2.0f * __builtin_amdgcn_rcpf(e + 1.0f);
}

// A[d][i][j] = w1_2[i][j] * w1_o[j][d]  (sample-independent; 8*64*64 f32 = 128 KB)
__global__ void __launch_bounds__(256) setupA(const float* __restrict__ w1_2,
                                              const float* __restrict__ w1_o,
                                              float* __restrict__ A) {
    int t = blockIdx.x * 256 + threadIdx.x;  // 0..32767
    int j = t & 63;
    int i = (t >> 6) & 63;
    int d = t >> 12;
    A[t] = w1_2[i * 64 + j] * w1_o[j * 8 + d];
}

// Pin exactly 2 waves/EU: register budget 256, no occupancy reward for
// spilling below it. (launch_bounds(256,2) alone let the allocator spill
// down to the 128-VGPR / 4-wave tier: 1.2 GB scratch traffic in round 2.)
__global__ void __launch_bounds__(256)
__attribute__((amdgpu_waves_per_eu(2, 2))) cnf_main(
    const float* __restrict__ tp, const float* __restrict__ zp,
    const float* __restrict__ w1_0, const float* __restrict__ b1_0,
    const float* __restrict__ w1_1, const float* __restrict__ b1_1,
    const float* __restrict__ w1_2, const float* __restrict__ b1_2,
    const float* __restrict__ w1_o, const float* __restrict__ b1_o,
    const float* __restrict__ w2_0, const float* __restrict__ b2_0,
    const float* __restrict__ w2_1, const float* __restrict__ b2_1,
    const float* __restrict__ w2_2, const float* __restrict__ b2_2,
    const float* __restrict__ w2_o, const float* __restrict__ b2_o,
    const float* __restrict__ A,
    float* __restrict__ out)
{
    const int idx = blockIdx.x * blockDim.x + threadIdx.x;
    const float tt = tp[0];

    float4 z0 = *reinterpret_cast<const float4*>(zp + (size_t)idx * 8);
    float4 z1 = *reinterpret_cast<const float4*>(zp + (size_t)idx * 8 + 4);
    float z[DD] = {z0.x, z0.y, z0.z, z0.w, z1.x, z1.y, z1.z, z1.w};

    // ---- net1 L0: xa = tanh([t,z] @ w1_0 + b1_0) ----
    float xa[HH];
    #pragma unroll
    for (int j = 0; j < HH; ++j) {
        float u = b1_0[j] + tt * w1_0[j];
        #pragma unroll
        for (int d = 0; d < DD; ++d) u = fmaf(z[d], w1_0[(d + 1) * HH + j], u);
        xa[j] = tanh_fast(u);
    }

    // ---- net1 L1: xb = tanh(xa @ w1_1 + b1_1) ----
    float xb[HH];
    #pragma unroll
    for (int j = 0; j < HH; ++j) {
        float u0 = b1_1[j], u1 = 0.0f;
        #pragma unroll
        for (int i = 0; i < HH; i += 2) {
            u0 = fmaf(xa[i],     w1_1[i * HH + j],       u0);
            u1 = fmaf(xa[i + 1], w1_1[(i + 1) * HH + j], u1);
        }
        xb[j] = tanh_fast(u0 + u1);
    }

    // pack t1 = 1 - xa^2 as f16 pairs; xa dies here
    __half2 t1h[HH / 2];
    #pragma unroll
    for (int k = 0; k < HH; k += 2) {
        t1h[k >> 1] = __floats2half2_rn(fmaf(-xa[k], xa[k], 1.0f),
                                        fmaf(-xa[k + 1], xa[k + 1], 1.0f));
    }

    // ---- net1 L2 + output layer streamed; t3 = 1 - x3^2 kept in f32 ----
    float t3[HH];
    float acc[DD];
    #pragma unroll
    for (int d = 0; d < DD; ++d) acc[d] = b1_o[d];
    #pragma unroll
    for (int j = 0; j < HH; ++j) {
        float u0 = b1_2[j], u1 = 0.0f;
        #pragma unroll
        for (int i = 0; i < HH; i += 2) {
            u0 = fmaf(xb[i],     w1_2[i * HH + j],       u0);
            u1 = fmaf(xb[i + 1], w1_2[(i + 1) * HH + j], u1);
        }
        float e = tanh_fast(u0 + u1);
        t3[j] = fmaf(-e, e, 1.0f);
        #pragma unroll
        for (int d = 0; d < DD; ++d) acc[d] = fmaf(e, w1_o[j * DD + d], acc[d]);
    }

    // pack t2 = 1 - xb^2 as f16 pairs; xb dies here
    __half2 t2h[HH / 2];
    #pragma unroll
    for (int k = 0; k < HH; k += 2) {
        t2h[k >> 1] = __floats2half2_rn(fmaf(-xb[k], xb[k], 1.0f),
                                        fmaf(-xb[k + 1], xb[k + 1], 1.0f));
    }

    // store dz_dt
    float4 o0 = {acc[0], acc[1], acc[2], acc[3]};
    float4 o1 = {acc[4], acc[5], acc[6], acc[7]};
    *reinterpret_cast<float4*>(out + (size_t)idx * 8) = o0;
    *reinterpret_cast<float4*>(out + (size_t)idx * 8 + 4) = o1;

    // ---- exact trace: 8 reverse sweeps; sA folded into A_d ----
    // live arrays: t1h(32) t2h(32) t3(64) sB(64) = 192 VGPRs
    float trace = 0.0f;
    #pragma unroll 1
    for (int d = 0; d < DD; ++d) {
        const float* __restrict__ Ad = A + d * (HH * HH);
        const float* __restrict__ W0zd = w1_0 + (d + 1) * HH;
        float sB[HH];
        #pragma unroll
        for (int i = 0; i < HH; ++i) {
            float r0 = 0.0f, r1 = 0.0f;
            #pragma unroll
            for (int j = 0; j < HH; j += 2) {
                r0 = fmaf(Ad[i * HH + j],     t3[j],     r0);
                r1 = fmaf(Ad[i * HH + j + 1], t3[j + 1], r1);
            }
            float t2i = (i & 1) ? __high2float(t2h[i >> 1]) : __low2float(t2h[i >> 1]);
            sB[i] = t2i * (r0 + r1);
        }
        #pragma unroll
        for (int k = 0; k < HH; ++k) {
            float q0 = 0.0f, q1 = 0.0f;
            #pragma unroll
            for (int i = 0; i < HH; i += 2) {
                q0 = fmaf(w1_1[k * HH + i],     sB[i],     q0);
                q1 = fmaf(w1_1[k * HH + i + 1], sB[i + 1], q1);
            }
            float t1k = (k & 1) ? __high2float(t1h[k >> 1]) : __low2float(t1h[k >> 1]);
            trace = fmaf(t1k * W0zd[k], q0 + q1, trace);
        }
    }

    // ---- net2 forward (z reloaded; trace arrays dead) ----
    z0 = *reinterpret_cast<const float4*>(zp + (size_t)idx * 8);
    z1 = *reinterpret_cast<const float4*>(zp + (size_t)idx * 8 + 4);
    float z2[DD] = {z0.x, z0.y, z0.z, z0.w, z1.x, z1.y, z1.z, z1.w};

    float ya[HH];
    #pragma unroll
    for (int j = 0; j < HH; ++j) {
        float u = b2_0[j] + tt * w2_0[j];
        #pragma unroll
        for (int d = 0; d < DD; ++d) u = fmaf(z2[d], w2_0[(d + 1) * HH + j], u);
        ya[j] = tanh_fast(u);
    }
    float yb[HH];
    #pragma unroll
    for (int j = 0; j < HH; ++j) {
        float u0 = b2_1[j], u1 = 0.0f;
        #pragma unroll
        for (int i = 0; i < HH; i += 2) {
            u0 = fmaf(ya[i],     w2_1[i * HH + j],       u0);
            u1 = fmaf(ya[i + 1], w2_1[(i + 1) * HH + j], u1);
        }
        yb[j] = tanh_fast(u0 + u1);
    }
    float g = b2_o[0];
    #pragma unroll
    for (int j = 0; j < HH; ++j) {
        float u0 = b2_2[j], u1 = 0.0f;
        #pragma unroll
        for (int i = 0; i < HH; i += 2) {
            u0 = fmaf(yb[i],     w2_2[i * HH + j],       u0);
            u1 = fmaf(yb[i + 1], w2_2[(i + 1) * HH + j], u1);
        }
        g = fmaf(tanh_fast(u0 + u1), w2_o[j], g);
    }

    out[(size_t)BATCH * 8 + idx] = g - trace;  // dlogp_z_dt
    out[(size_t)BATCH * 9 + idx] = g;          // g
}

extern "C" void kernel_launch(void* const* d_in, const int* in_sizes, int n_in,
                              void* d_out, int out_size, void* d_ws, size_t ws_size,
                              hipStream_t stream) {
    const float* tp   = (const float*)d_in[0];
    const float* zp   = (const float*)d_in[1];
    // d_in[2] = logp_z (unused)
    const float* w1_0 = (const float*)d_in[3];
    const float* b1_0 = (const float*)d_in[4];
    const float* w1_1 = (const float*)d_in[5];
    const float* b1_1 = (const float*)d_in[6];
    const float* w1_2 = (const float*)d_in[7];
    const float* b1_2 = (const float*)d_in[8];
    const float* w1_o = (const float*)d_in[9];
    const float* b1_o = (const float*)d_in[10];
    const float* w2_0 = (const float*)d_in[11];
    const float* b2_0 = (const float*)d_in[12];
    const float* w2_1 = (const float*)d_in[13];
    const float* b2_1 = (const float*)d_in[14];
    const float* w2_2 = (const float*)d_in[15];
    const float* b2_2 = (const float*)d_in[16];
    const float* w2_o = (const float*)d_in[17];
    const float* b2_o = (const float*)d_in[18];
    float* out = (float*)d_out;
    float* A   = (float*)d_ws;   // 8*64*64 f32 = 128 KB

    hipLaunchKernelGGL(setupA, dim3(128), dim3(256), 0, stream, w1_2, w1_o, A);
    hipLaunchKernelGGL(cnf_main, dim3(BATCH / 256), dim3(256), 0, stream,
                       tp, zp, w1_0, b1_0, w1_1, b1_1, w1_2, b1_2, w1_o, b1_o,
                       w2_0, b2_0, w2_1, b2_1, w2_2, b2_2, w2_o, b2_o, A, out);
}

// Round 4
// 186.319 us; speedup vs baseline: 24.9250x; 24.9250x over previous
//
#include <hip/hip_runtime.h>

// CNF: B=262144 samples, D=8, H=64.  outputs: dz_dt (B*8) | dlogp (B) | g (B), f32.
// f16 MFMA formulation: transposed GEMMs (features=M, samples=N=16 per wave).
// ws holds pre-swizzled weight fragments (prep kernel).

#define BATCH 262144

typedef _Float16 h16;
typedef __attribute__((ext_vector_type(8))) _Float16 half8;
typedef __attribute__((ext_vector_type(4))) float f32x4;

#define MFMA16(a, b, c) __builtin_amdgcn_mfma_f32_16x16x32_f16((a), (b), (c), 0, 0, 0)

// ws byte layout
#define WS_A   0        // 60 A-frag slots: [slot][lane 0..63][8 h16] = 60 KiB
#define WS_WO  61440    // woT_pk: [d 0..7][k 0..63] h16 = 1 KiB
#define WS_E   62464    // E_lay:  [d][g][mt*4+r] f32 = 2 KiB
#define WS_B   64512    // blay:   [6 layers][64] f32 (D-layout index g*16+mt*4+r)
#define WS_BO  66048    // bo_lay: [16] f32 (b1_o in D-layout rows, 0-padded)

__device__ __forceinline__ float tanh_fast(float x) {
    float e = __builtin_amdgcn_exp2f(x * 2.8853900817779268f); // 2*log2(e)
    return 1.0f - 2.0f * __builtin_amdgcn_rcpf(e + 1.0f);
}

// ---------------- prep: build weight fragments in ws ----------------
// A-frag mapping (operand A, M x K per 16x16x32): lane l holds
//   m = mt*16 + (l&15),  k = ks*32 + (l>>4)*8 + kk   (kk = 0..7)
// slots: 0..3 net1-W0^T | 4..11 net1-W1^T | 12..19 net1-W2^T | 20..21 Wo^T
//        22..25 net2-W0^T | 26..33 net2-W1^T | 34..41 net2-W2^T | 42..43 w2o^T
//        44..51 w1_2 direct (trace G1) | 52..59 w1_1 direct (trace G2)
__global__ void __launch_bounds__(256) prep(
    const float* __restrict__ w1_0, const float* __restrict__ w1_1,
    const float* __restrict__ w1_2, const float* __restrict__ w1_o,
    const float* __restrict__ w2_0, const float* __restrict__ w2_1,
    const float* __restrict__ w2_2, const float* __restrict__ w2_o,
    const float* __restrict__ b1_0, const float* __restrict__ b1_1,
    const float* __restrict__ b1_2, const float* __restrict__ b1_o,
    const float* __restrict__ b2_0, const float* __restrict__ b2_1,
    const float* __restrict__ b2_2, char* __restrict__ ws)
{
    int t = blockIdx.x * 256 + threadIdx.x;
    if (t < 3840) {                     // A-frag tasks: (slot, lane)
        int slot = t >> 6, lane = t & 63;
        int mrow = lane & 15, kg = lane >> 4;
        half8 v;
        #pragma unroll
        for (int kk = 0; kk < 8; ++kk) {
            int mt = 0, ks = 0;
            float val = 0.0f;
            if (slot < 4) {                     // net1 W0^T, K=9 padded to 32
                mt = slot; int k = kg * 8 + kk; int m = mt * 16 + mrow;
                val = (k < 9) ? w1_0[k * 64 + m] : 0.0f;
            } else if (slot < 12) {             // net1 W1^T
                int s = slot - 4; mt = s >> 1; ks = s & 1;
                int k = ks * 32 + kg * 8 + kk; int m = mt * 16 + mrow;
                val = w1_1[k * 64 + m];
            } else if (slot < 20) {             // net1 W2^T
                int s = slot - 12; mt = s >> 1; ks = s & 1;
                int k = ks * 32 + kg * 8 + kk; int m = mt * 16 + mrow;
                val = w1_2[k * 64 + m];
            } else if (slot < 22) {             // Wo^T (8x64), rows >=8 zero
                ks = slot - 20; int k = ks * 32 + kg * 8 + kk;
                val = (mrow < 8) ? w1_o[k * 8 + mrow] : 0.0f;
            } else if (slot < 26) {             // net2 W0^T
                mt = slot - 22; int k = kg * 8 + kk; int m = mt * 16 + mrow;
                val = (k < 9) ? w2_0[k * 64 + m] : 0.0f;
            } else if (slot < 34) {             // net2 W1^T
                int s = slot - 26; mt = s >> 1; ks = s & 1;
                int k = ks * 32 + kg * 8 + kk; int m = mt * 16 + mrow;
                val = w2_1[k * 64 + m];
            } else if (slot < 42) {             // net2 W2^T
                int s = slot - 34; mt = s >> 1; ks = s & 1;
                int k = ks * 32 + kg * 8 + kk; int m = mt * 16 + mrow;
                val = w2_2[k * 64 + m];
            } else if (slot < 44) {             // w2_o^T (1x64), row 0 only
                ks = slot - 42; int k = ks * 32 + kg * 8 + kk;
                val = (mrow == 0) ? w2_o[k] : 0.0f;
            } else if (slot < 52) {             // w1_2 direct (trace G1)
                int s = slot - 44; mt = s >> 1; ks = s & 1;
                int k = ks * 32 + kg * 8 + kk; int m = mt * 16 + mrow;
                val = w1_2[m * 64 + k];
            } else {                            // w1_1 direct (trace G2)
                int s = slot - 52; mt = s >> 1; ks = s & 1;
                int k = ks * 32 + kg * 8 + kk; int m = mt * 16 + mrow;
                val = w1_1[m * 64 + k];
            }
            v[kk] = (h16)val;
        }
        *(half8*)((h16*)(ws + WS_A) + (size_t)slot * 512 + (size_t)lane * 8) = v;
    } else if (t < 4352) {              // woT_pk[d][k] = w1_o[k,d]
        int e = t - 3840; int d = e >> 6, k = e & 63;
        ((h16*)(ws + WS_WO))[e] = (h16)w1_o[k * 8 + d];
    } else if (t < 4864) {              // E_lay[d][g][mt*4+r] = w1_0[(d+1)*64 + 16mt+4g+r]
        int e = t - 4352; int d = e >> 6, g = (e >> 4) & 3, tr = e & 15;
        int mt = tr >> 2, r = tr & 3;
        int k = 16 * mt + 4 * g + r;
        ((float*)(ws + WS_E))[e] = w1_0[(d + 1) * 64 + k];
    } else if (t < 5248) {              // blay[layer][g*16+mt*4+r] = b[16mt+4g+r]
        int e = t - 4864; int layer = e >> 6, i = e & 63;
        int g = i >> 4, mt = (i >> 2) & 3, r = i & 3;
        int m = 16 * mt + 4 * g + r;
        const float* bsrc = (layer == 0) ? b1_0 : (layer == 1) ? b1_1 :
                            (layer == 2) ? b1_2 : (layer == 3) ? b2_0 :
                            (layer == 4) ? b2_1 : b2_2;
        ((float*)(ws + WS_B))[e] = bsrc[m];
    } else if (t < 5264) {              // bo_lay[g*4+r] = b1_o[4g+r] (0 for m>=8)
        int i = t - 5248; int g = i >> 2, r = i & 3;
        int m = 4 * g + r;
        ((float*)(ws + WS_BO))[i] = (m < 8) ? b1_o[m] : 0.0f;
    }
}

// ---------------- main kernel ----------------
__global__ void __launch_bounds__(256) cnf_mfma(
    const float* __restrict__ tp, const float* __restrict__ zp,
    const float* __restrict__ b2_o, const char* __restrict__ ws,
    float* __restrict__ out)
{
    // per-wave private LDS tiles: [16 samples][64 feats] f16, XOR-swizzled
    __shared__ __align__(16) h16 xbuf[4][1024];
    __shared__ __align__(16) h16 t3buf[4][1024];

    const int lane = threadIdx.x & 63;
    const int wv = threadIdx.x >> 6;
    const int c = lane & 15;        // sample column within wave
    const int g = lane >> 4;        // lane k/m-group
    const int sIdx = blockIdx.x * 64 + wv * 16 + c;
    const int swz = (c & 7) << 3;   // element-index XOR swizzle

    const h16*   wsA  = (const h16*)(ws + WS_A);
    const h16*   wsWo = (const h16*)(ws + WS_WO);
    const float* wsE  = (const float*)(ws + WS_E);
    const float* wsB  = (const float*)(ws + WS_B);
    const float* wsBo = (const float*)(ws + WS_BO);
    h16* xb  = xbuf[wv];
    h16* t3b = t3buf[wv];

    const float tt = tp[0];
    const f32x4 zl = *(const f32x4*)(zp + (size_t)sIdx * 8);
    const f32x4 zh = *(const f32x4*)(zp + (size_t)sIdx * 8 + 4);

    // B-frag of input s^T = [t, z]^T (K=9 padded to 32): col=c, k=8g+kk
    half8 b0f;
    #pragma unroll
    for (int i = 0; i < 8; ++i) b0f[i] = (h16)0.0f;
    if (g == 0) {
        b0f[0] = (h16)tt;
        b0f[1] = (h16)zl[0]; b0f[2] = (h16)zl[1]; b0f[3] = (h16)zl[2];
        b0f[4] = (h16)zl[3]; b0f[5] = (h16)zh[0]; b0f[6] = (h16)zh[1];
        b0f[7] = (h16)zh[2];
    } else if (g == 1) {
        b0f[0] = (h16)zh[3];
    }

    f32x4 d[4], t1v[4], t2v[4];

    // ===== net1 L0: x1^T = tanh(W0^T s^T + b) =====
    #pragma unroll
    for (int mt = 0; mt < 4; ++mt) {
        f32x4 acc = *(const f32x4*)(wsB + 0 * 64 + g * 16 + mt * 4);
        d[mt] = MFMA16(*(const half8*)(wsA + (0 + mt) * 512 + lane * 8), b0f, acc);
    }
    #pragma unroll
    for (int mt = 0; mt < 4; ++mt) {
        union { h16 h[4]; uint2 u; } px;
        #pragma unroll
        for (int r = 0; r < 4; ++r) {
            float x = tanh_fast(d[mt][r]);
            t1v[mt][r] = fmaf(-x, x, 1.0f);
            px.h[r] = (h16)x;
        }
        *(uint2*)&xb[(c * 64 + mt * 16 + 4 * g) ^ swz] = px.u;
    }

    // ===== net1 L1 =====
    {
        half8 bf0 = *(const half8*)&xb[(c * 64 + 8 * g) ^ swz];
        half8 bf1 = *(const half8*)&xb[(c * 64 + 32 + 8 * g) ^ swz];
        #pragma unroll
        for (int mt = 0; mt < 4; ++mt) {
            f32x4 acc = *(const f32x4*)(wsB + 1 * 64 + g * 16 + mt * 4);
            acc = MFMA16(*(const half8*)(wsA + (4 + mt * 2) * 512 + lane * 8), bf0, acc);
            acc = MFMA16(*(const half8*)(wsA + (5 + mt * 2) * 512 + lane * 8), bf1, acc);
            d[mt] = acc;
        }
    }
    #pragma unroll
    for (int mt = 0; mt < 4; ++mt) {
        union { h16 h[4]; uint2 u; } px;
        #pragma unroll
        for (int r = 0; r < 4; ++r) {
            float x = tanh_fast(d[mt][r]);
            t2v[mt][r] = fmaf(-x, x, 1.0f);
            px.h[r] = (h16)x;
        }
        *(uint2*)&xb[(c * 64 + mt * 16 + 4 * g) ^ swz] = px.u;
    }

    // ===== net1 L2 (x3 -> xb, t3 -> t3b) =====
    {
        half8 bf0 = *(const half8*)&xb[(c * 64 + 8 * g) ^ swz];
        half8 bf1 = *(const half8*)&xb[(c * 64 + 32 + 8 * g) ^ swz];
        #pragma unroll
        for (int mt = 0; mt < 4; ++mt) {
            f32x4 acc = *(const f32x4*)(wsB + 2 * 64 + g * 16 + mt * 4);
            acc = MFMA16(*(const half8*)(wsA + (12 + mt * 2) * 512 + lane * 8), bf0, acc);
            acc = MFMA16(*(const half8*)(wsA + (13 + mt * 2) * 512 + lane * 8), bf1, acc);
            d[mt] = acc;
        }
    }
    #pragma unroll
    for (int mt = 0; mt < 4; ++mt) {
        union { h16 h[4]; uint2 u; } px, pt;
        #pragma unroll
        for (int r = 0; r < 4; ++r) {
            float x = tanh_fast(d[mt][r]);
            float tq = fmaf(-x, x, 1.0f);
            px.h[r] = (h16)x;
            pt.h[r] = (h16)tq;
        }
        int e = (c * 64 + mt * 16 + 4 * g) ^ swz;
        *(uint2*)&xb[e] = px.u;
        *(uint2*)&t3b[e] = pt.u;
    }

    // ===== dz_dt = Wo^T x3^T + b1_o  (M=8 in tile 0) =====
    {
        half8 bf0 = *(const half8*)&xb[(c * 64 + 8 * g) ^ swz];
        half8 bf1 = *(const half8*)&xb[(c * 64 + 32 + 8 * g) ^ swz];
        f32x4 dz = *(const f32x4*)(wsBo + g * 4);
        dz = MFMA16(*(const half8*)(wsA + 20 * 512 + lane * 8), bf0, dz);
        dz = MFMA16(*(const half8*)(wsA + 21 * 512 + lane * 8), bf1, dz);
        if (g < 2)
            *(f32x4*)(out + (size_t)sIdx * 8 + g * 4) = dz;
    }

    // ===== net2 (reuses b0f and xb) =====
    #pragma unroll
    for (int mt = 0; mt < 4; ++mt) {
        f32x4 acc = *(const f32x4*)(wsB + 3 * 64 + g * 16 + mt * 4);
        d[mt] = MFMA16(*(const half8*)(wsA + (22 + mt) * 512 + lane * 8), b0f, acc);
    }
    #pragma unroll
    for (int mt = 0; mt < 4; ++mt) {
        union { h16 h[4]; uint2 u; } px;
        #pragma unroll
        for (int r = 0; r < 4; ++r) px.h[r] = (h16)tanh_fast(d[mt][r]);
        *(uint2*)&xb[(c * 64 + mt * 16 + 4 * g) ^ swz] = px.u;
    }
    #pragma unroll 1
    for (int L = 0; L < 2; ++L) {   // net2 L1, L2
        int sbase = (L == 0) ? 26 : 34;
        half8 bf0 = *(const half8*)&xb[(c * 64 + 8 * g) ^ swz];
        half8 bf1 = *(const half8*)&xb[(c * 64 + 32 + 8 * g) ^ swz];
        #pragma unroll
        for (int mt = 0; mt < 4; ++mt) {
            f32x4 acc = *(const f32x4*)(wsB + (4 + L) * 64 + g * 16 + mt * 4);
            acc = MFMA16(*(const half8*)(wsA + (sbase + mt * 2) * 512 + lane * 8), bf0, acc);
            acc = MFMA16(*(const half8*)(wsA + (sbase + mt * 2 + 1) * 512 + lane * 8), bf1, acc);
            d[mt] = acc;
        }
        #pragma unroll
        for (int mt = 0; mt < 4; ++mt) {
            union { h16 h[4]; uint2 u; } px;
            #pragma unroll
            for (int r = 0; r < 4; ++r) px.h[r] = (h16)tanh_fast(d[mt][r]);
            *(uint2*)&xb[(c * 64 + mt * 16 + 4 * g) ^ swz] = px.u;
        }
    }
    float gval;
    {
        half8 bf0 = *(const half8*)&xb[(c * 64 + 8 * g) ^ swz];
        half8 bf1 = *(const half8*)&xb[(c * 64 + 32 + 8 * g) ^ swz];
        float b2 = b2_o[0];
        f32x4 acc = {b2, 0.0f, 0.0f, 0.0f};
        acc = MFMA16(*(const half8*)(wsA + 42 * 512 + lane * 8), bf0, acc);
        acc = MFMA16(*(const half8*)(wsA + 43 * 512 + lane * 8), bf1, acc);
        gval = acc[0];   // valid at g==0 (row m=0)
    }

    // ===== trace: 8 tangents, 2 GEMMs each =====
    float tr = 0.0f;
    #pragma unroll 1
    for (int d0 = 0; d0 < 8; ++d0) {
        // E in D-layout
        f32x4 e0 = *(const f32x4*)(wsE + d0 * 64 + g * 16 + 0);
        f32x4 e1 = *(const f32x4*)(wsE + d0 * 64 + g * 16 + 4);
        f32x4 e2 = *(const f32x4*)(wsE + d0 * 64 + g * 16 + 8);
        f32x4 e3 = *(const f32x4*)(wsE + d0 * 64 + g * 16 + 12);
        // sA^T = t3 ∘ wo[:,d0]  (B-frag, f16)
        half8 w0f = *(const half8*)(wsWo + d0 * 64 + 8 * g);
        half8 w1f = *(const half8*)(wsWo + d0 * 64 + 32 + 8 * g);
        half8 t3f0 = *(const half8*)&t3b[(c * 64 + 8 * g) ^ swz];
        half8 t3f1 = *(const half8*)&t3b[(c * 64 + 32 + 8 * g) ^ swz];
        half8 sA0 = t3f0 * w0f;
        half8 sA1 = t3f1 * w1f;
        // G1: r = W2 sA^T  (A = w1_2 direct, slots 44..51)
        f32x4 rr[4];
        #pragma unroll
        for (int mt = 0; mt < 4; ++mt) {
            f32x4 acc = {0.0f, 0.0f, 0.0f, 0.0f};
            acc = MFMA16(*(const half8*)(wsA + (44 + mt * 2) * 512 + lane * 8), sA0, acc);
            acc = MFMA16(*(const half8*)(wsA + (45 + mt * 2) * 512 + lane * 8), sA1, acc);
            rr[mt] = acc;
        }
        // sB = t2 ∘ r  -> xb
        #pragma unroll
        for (int mt = 0; mt < 4; ++mt) {
            union { h16 h[4]; uint2 u; } px;
            #pragma unroll
            for (int r = 0; r < 4; ++r)
                px.h[r] = (h16)(t2v[mt][r] * rr[mt][r]);
            *(uint2*)&xb[(c * 64 + mt * 16 + 4 * g) ^ swz] = px.u;
        }
        half8 sb0 = *(const half8*)&xb[(c * 64 + 8 * g) ^ swz];
        half8 sb1 = *(const half8*)&xb[(c * 64 + 32 + 8 * g) ^ swz];
        // G2: q = W1 sB^T  (A = w1_1 direct, slots 52..59)
        #pragma unroll
        for (int mt = 0; mt < 4; ++mt) {
            f32x4 acc = {0.0f, 0.0f, 0.0f, 0.0f};
            acc = MFMA16(*(const half8*)(wsA + (52 + mt * 2) * 512 + lane * 8), sb0, acc);
            acc = MFMA16(*(const half8*)(wsA + (53 + mt * 2) * 512 + lane * 8), sb1, acc);
            d[mt] = acc;
        }
        // tr += sum_k q[k] * t1[k] * E[d0,k]
        #pragma unroll
        for (int r = 0; r < 4; ++r) {
            tr = fmaf(d[0][r] * t1v[0][r], e0[r], tr);
            tr = fmaf(d[1][r] * t1v[1][r], e1[r], tr);
            tr = fmaf(d[2][r] * t1v[2][r], e2[r], tr);
            tr = fmaf(d[3][r] * t1v[3][r], e3[r], tr);
        }
    }
    // reduce across the 4 lane-groups (k-partials): lanes c, c+16, c+32, c+48
    tr += __shfl_xor(tr, 16);
    tr += __shfl_xor(tr, 32);

    if (g == 0) {
        out[(size_t)BATCH * 8 + sIdx] = gval - tr;  // dlogp_z_dt
        out[(size_t)BATCH * 9 + sIdx] = gval;       // g
    }
}

extern "C" void kernel_launch(void* const* d_in, const int* in_sizes, int n_in,
                              void* d_out, int out_size, void* d_ws, size_t ws_size,
                              hipStream_t stream) {
    const float* tp   = (const float*)d_in[0];
    const float* zp   = (const float*)d_in[1];
    // d_in[2] = logp_z (unused)
    const float* w1_0 = (const float*)d_in[3];
    const float* b1_0 = (const float*)d_in[4];
    const float* w1_1 = (const float*)d_in[5];
    const float* b1_1 = (const float*)d_in[6];
    const float* w1_2 = (const float*)d_in[7];
    const float* b1_2 = (const float*)d_in[8];
    const float* w1_o = (const float*)d_in[9];
    const float* b1_o = (const float*)d_in[10];
    const float* w2_0 = (const float*)d_in[11];
    const float* b2_0 = (const float*)d_in[12];
    const float* w2_1 = (const float*)d_in[13];
    const float* b2_1 = (const float*)d_in[14];
    const float* w2_2 = (const float*)d_in[15];
    const float* b2_2 = (const float*)d_in[16];
    const float* w2_o = (const float*)d_in[17];
    const float* b2_o = (const float*)d_in[18];

    char* ws = (char*)d_ws;
    float* out = (float*)d_out;

    hipLaunchKernelGGL(prep, dim3(21), dim3(256), 0, stream,
                       w1_0, w1_1, w1_2, w1_o, w2_0, w2_1, w2_2, w2_o,
                       b1_0, b1_1, b1_2, b1_o, b2_0, b2_1, b2_2, ws);
    hipLaunchKernelGGL(cnf_mfma, dim3(BATCH / 64), dim3(256), 0, stream,
                       tp, zp, b2_o, ws, out);
}